// Round 5
// baseline (74.827 us; speedup 1.0000x reference)
//
#include <hip/hip_runtime.h>

// out[n, d*W + w] = x[n + w - H, d] if source token in same sequence, else 0.
// W=5, H=2, D=1024, 8 sequences, N=16384.
//
// Block = 16 tokens (256 threads), D split into 2 half-passes (512 cols each)
// so LDS = 20 rows x 512 floats = 40 KB -> 4 blocks/CU, grid = 1024 = all
// blocks resident at once (no tail rounds). Staging uses global_load_lds
// (16B, linear dest). Output floats for a d-half are a contiguous p-range,
// so every nontemporal f32x4 store instruction stays 64x16B contiguous.
// Fetch redundancy 20/16 = 1.25x, boundary overlap L2-absorbed via
// XCD-chunked block swizzle.

#define WIN 5
#define HALF 2
#define DIM 1024
#define DV (DIM / 4)         // 256 f32x4 per x row
#define OUTV (DV * WIN)      // 1280 f32x4 per out row
#define NSEQ 8
#define T 16                 // tokens per block
#define ROWS (T + 2 * HALF)  // 20 staged rows
#define HD (DIM / 2)         // 512 floats per half-row
#define HOUTV (OUTV / 2)     // 640 f32x4 per out half-row

typedef float f32x4 __attribute__((ext_vector_type(4)));

__device__ inline void gload_lds16(const float* g, float* l) {
    __builtin_amdgcn_global_load_lds(
        (const __attribute__((address_space(1))) void*)g,
        (__attribute__((address_space(3))) void*)l,
        16, 0, 0);
}

__global__ __launch_bounds__(256) void inflate_kernel(
    const float* __restrict__ x,        // [N][DIM]
    const int*   __restrict__ lengths,  // [NSEQ]
    f32x4*       __restrict__ out4,     // [N][OUTV]
    int N)
{
    __shared__ float lds[ROWS * HD];    // 40 KB, lds[rr*HD + dl]

    // Bijective XCD-chunked swizzle (gridDim.x = 1024, divisible by 8).
    const int nb    = gridDim.x;
    const int chunk = nb >> 3;
    const int bid   = blockIdx.x;
    const int newb  = (bid & 7) * chunk + (bid >> 3);
    const int t0    = newb * T;

    const int g    = threadIdx.x;
    const int wid  = g >> 6;
    const int lane = g & 63;

    int Ls[NSEQ];
#pragma unroll
    for (int s = 0; s < NSEQ; ++s) Ls[s] = lengths[s];

#pragma unroll
    for (int hp = 0; hp < 2; ++hp) {
        if (hp) __syncthreads();        // LDS reuse across passes

        // Phase 1: stage 20 half-rows = 40 wave-chunks of 1 KB each.
        // Chunk c: row rr = c>>1, sub-half sub = c&1 (256 floats).
#pragma unroll
        for (int i = 0; i < (ROWS * 2) / 4; ++i) {   // 10 iters
            const int c   = i * 4 + wid;             // wave-uniform
            const int rr  = c >> 1;
            const int sub = c & 1;
            const int gr  = t0 - HALF + rr;
            float* lbase = lds + rr * HD + sub * 256;
            if (gr >= 0 && gr < N) {
                const float* gsrc = x + (size_t)gr * DIM + hp * HD
                                      + sub * 256 + lane * 4;
                gload_lds16(gsrc, lbase);
            } else {
                *(f32x4*)(lbase + lane * 4) = (f32x4)0.f;
            }
        }
        __syncthreads();

        // Phase 2: wave emits 4 tokens' output half-rows.
#pragma unroll
        for (int ti = 0; ti < 4; ++ti) {
            const int tt = wid * 4 + ti;     // 0..15, wave-uniform
            const int n  = t0 + tt;

            // Owning sequence (wave-uniform).
            int start = 0, end = N, acc = 0;
#pragma unroll
            for (int s = 0; s < NSEQ; ++s) {
                const int L = Ls[s];
                if (n >= acc && n < acc + L) { start = acc; end = acc + L; }
                acc += L;
            }
            int wlo = start - n + HALF; if (wlo < 0) wlo = 0;
            int whi = end - n + HALF - 1; if (whi > WIN - 1) whi = WIN - 1;

            f32x4* dst = out4 + (size_t)n * OUTV + hp * HOUTV;

            if (wlo == 0 && whi == WIN - 1) {
#pragma unroll
                for (int k = 0; k < HOUTV / 64; ++k) {   // 10 iters
                    const unsigned jl = k * 64 + lane;
                    const unsigned pg = hp * (HOUTV * 4) + 4 * jl;
                    f32x4 o;
                    { unsigned p = pg + 0, d = p / WIN, w = p - WIN * d;
                      o.x = lds[(tt + w) * HD + (d - hp * HD)]; }
                    { unsigned p = pg + 1, d = p / WIN, w = p - WIN * d;
                      o.y = lds[(tt + w) * HD + (d - hp * HD)]; }
                    { unsigned p = pg + 2, d = p / WIN, w = p - WIN * d;
                      o.z = lds[(tt + w) * HD + (d - hp * HD)]; }
                    { unsigned p = pg + 3, d = p / WIN, w = p - WIN * d;
                      o.w = lds[(tt + w) * HD + (d - hp * HD)]; }
                    __builtin_nontemporal_store(o, &dst[jl]);
                }
            } else {
#pragma unroll
                for (int k = 0; k < HOUTV / 64; ++k) {
                    const unsigned jl = k * 64 + lane;
                    const unsigned pg = hp * (HOUTV * 4) + 4 * jl;
                    f32x4 o;
                    { unsigned p = pg + 0, d = p / WIN; int w = (int)(p - WIN * d);
                      o.x = (w >= wlo && w <= whi) ? lds[(tt + w) * HD + (d - hp * HD)] : 0.f; }
                    { unsigned p = pg + 1, d = p / WIN; int w = (int)(p - WIN * d);
                      o.y = (w >= wlo && w <= whi) ? lds[(tt + w) * HD + (d - hp * HD)] : 0.f; }
                    { unsigned p = pg + 2, d = p / WIN; int w = (int)(p - WIN * d);
                      o.z = (w >= wlo && w <= whi) ? lds[(tt + w) * HD + (d - hp * HD)] : 0.f; }
                    { unsigned p = pg + 3, d = p / WIN; int w = (int)(p - WIN * d);
                      o.w = (w >= wlo && w <= whi) ? lds[(tt + w) * HD + (d - hp * HD)] : 0.f; }
                    __builtin_nontemporal_store(o, &dst[jl]);
                }
            }
        }
    }
}

extern "C" void kernel_launch(void* const* d_in, const int* in_sizes, int n_in,
                              void* d_out, int out_size, void* d_ws, size_t ws_size,
                              hipStream_t stream) {
    const float* x       = (const float*)d_in[0];
    const int*   lengths = (const int*)d_in[1];
    float*       out     = (float*)d_out;

    const int N = in_sizes[0] / DIM;    // 16384

    dim3 grid(N / T), block(256);       // 1024 blocks
    hipLaunchKernelGGL(inflate_kernel, grid, block, 0, stream,
                       x, lengths, (f32x4*)out, N);
}

// Round 6
// 72.468 us; speedup vs baseline: 1.0326x; 1.0326x over previous
//
#include <hip/hip_runtime.h>

// out[n, d*W + w] = x[n + w - H, d] if source token in same sequence, else 0.
// W=5, H=2, D=1024, 8 sequences, N=16384.
//
// Block = 8 consecutive tokens (256 threads). Stage 12 x-rows (tokens-2..+9,
// zero-clamped at [0,N)) into LDS, then each wave emits 2 full output rows
// with fully-coalesced nontemporal float4 stores; the d*W+w transpose is
// resolved by scalar LDS reads. Sequence-boundary masking only on the
// wave-uniform slow path. XCD-chunked blockIdx swizzle keeps the 5-row
// overlap between neighboring blocks inside one XCD's L2.
//
// Measured 72.1 us (R4) ~ 90% of the 403 MB / 6.3 TB/s mixed-stream floor.
// R5's T=16 half-D + global_load_lds restructure regressed (74.8) -> reverted.

#define WIN 5
#define HALF 2
#define DIM 1024
#define DV (DIM / 4)        // 256 float4 per x row
#define OUTV (DV * WIN)     // 1280 float4 per out row
#define NSEQ 8
#define T 8                 // tokens per block
#define ROWS (T + 2 * HALF) // 12 staged rows

typedef float f32x4 __attribute__((ext_vector_type(4)));

__global__ __launch_bounds__(256) void inflate_kernel(
    const f32x4* __restrict__ x4,       // [N][DV]
    const int*   __restrict__ lengths,  // [NSEQ]
    f32x4*       __restrict__ out4,     // [N][OUTV]
    int N)
{
    __shared__ float lds[ROWS * DIM];   // 48 KB

    // Bijective XCD-chunked swizzle (gridDim.x = 2048, divisible by 8).
    const int nb    = gridDim.x;
    const int chunk = nb >> 3;
    const int bid   = blockIdx.x;
    const int newb  = (bid & 7) * chunk + (bid >> 3);
    const int t0    = newb * T;

    const int g = threadIdx.x;

    // Phase 1: stage rows t0-2 .. t0+9 (zero outside [0,N)).
    f32x4* lds4 = (f32x4*)lds;
#pragma unroll
    for (int rr = 0; rr < ROWS; ++rr) {
        const int gr = t0 - HALF + rr;
        f32x4 v = (f32x4)0.f;
        if (gr >= 0 && gr < N) v = x4[(size_t)gr * DV + g];
        lds4[rr * DV + g] = v;
    }

    // Hoist lengths into registers (uniform).
    int Ls[NSEQ];
#pragma unroll
    for (int s = 0; s < NSEQ; ++s) Ls[s] = lengths[s];

    __syncthreads();

    // Phase 2: wave wid emits tokens t0 + 2*wid + {0,1}.
    const int wid  = g >> 6;
    const int lane = g & 63;

#pragma unroll
    for (int ti = 0; ti < 2; ++ti) {
        const int tt = wid * 2 + ti;      // 0..7, wave-uniform
        const int n  = t0 + tt;

        // Owning sequence (wave-uniform).
        int start = 0, end = N, acc = 0;
#pragma unroll
        for (int s = 0; s < NSEQ; ++s) {
            const int L = Ls[s];
            if (n >= acc && n < acc + L) { start = acc; end = acc + L; }
            acc += L;
        }
        int wlo = start - n + HALF; if (wlo < 0) wlo = 0;
        int whi = end - n + HALF - 1; if (whi > WIN - 1) whi = WIN - 1;

        const float* ldsbase = lds + tt * DIM;   // + w*DIM + d
        f32x4* dst = out4 + (size_t)n * OUTV;

        if (wlo == 0 && whi == WIN - 1) {
#pragma unroll
            for (int k = 0; k < OUTV / 64; ++k) {   // 20 iters
                const unsigned j  = k * 64 + lane;
                const unsigned p0 = 4 * j;
                f32x4 o;
                { unsigned p = p0 + 0, d = p / WIN, w = p - d * WIN; o.x = ldsbase[w * DIM + d]; }
                { unsigned p = p0 + 1, d = p / WIN, w = p - d * WIN; o.y = ldsbase[w * DIM + d]; }
                { unsigned p = p0 + 2, d = p / WIN, w = p - d * WIN; o.z = ldsbase[w * DIM + d]; }
                { unsigned p = p0 + 3, d = p / WIN, w = p - d * WIN; o.w = ldsbase[w * DIM + d]; }
                __builtin_nontemporal_store(o, &dst[j]);
            }
        } else {
#pragma unroll
            for (int k = 0; k < OUTV / 64; ++k) {
                const unsigned j  = k * 64 + lane;
                const unsigned p0 = 4 * j;
                f32x4 o;
                { unsigned p = p0 + 0, d = p / WIN; int w = (int)(p - d * WIN);
                  o.x = (w >= wlo && w <= whi) ? ldsbase[w * DIM + d] : 0.f; }
                { unsigned p = p0 + 1, d = p / WIN; int w = (int)(p - d * WIN);
                  o.y = (w >= wlo && w <= whi) ? ldsbase[w * DIM + d] : 0.f; }
                { unsigned p = p0 + 2, d = p / WIN; int w = (int)(p - d * WIN);
                  o.z = (w >= wlo && w <= whi) ? ldsbase[w * DIM + d] : 0.f; }
                { unsigned p = p0 + 3, d = p / WIN; int w = (int)(p - d * WIN);
                  o.w = (w >= wlo && w <= whi) ? ldsbase[w * DIM + d] : 0.f; }
                __builtin_nontemporal_store(o, &dst[j]);
            }
        }
    }
}

extern "C" void kernel_launch(void* const* d_in, const int* in_sizes, int n_in,
                              void* d_out, int out_size, void* d_ws, size_t ws_size,
                              hipStream_t stream) {
    const float* x       = (const float*)d_in[0];
    const int*   lengths = (const int*)d_in[1];
    float*       out     = (float*)d_out;

    const int N = in_sizes[0] / DIM;    // 16384

    dim3 grid(N / T), block(256);
    hipLaunchKernelGGL(inflate_kernel, grid, block, 0, stream,
                       (const f32x4*)x, lengths, (f32x4*)out, N);
}